// Round 7
// baseline (180.772 us; speedup 1.0000x reference)
//
#include <hip/hip_runtime.h>

typedef __bf16 bf16;
typedef __bf16 bf16x4 __attribute__((ext_vector_type(4)));
typedef __bf16 bf16x8 __attribute__((ext_vector_type(8)));
typedef float f32x4 __attribute__((ext_vector_type(4)));
typedef short s16x4 __attribute__((ext_vector_type(4)));
typedef unsigned int u32;
typedef unsigned long long u64;

#define B_ 2
#define H_ 8
#define L_ 2048
#define D_ 128
#define F_ 128
#define QT 128
#define KT 64
#define NKT (L_ / KT)
#define NQT (L_ / QT)

// workspace layout (bytes)
#define WS_KB 0u            // Kb  : bf16 [b][k][16B-chunk swizzled], 1 MB
#define WS_VT (1u << 20)    // Vtb : bf16 [b][kt][fragment blocks], 1 MB
#define WS_MB (2u << 20)    // bits: u64 [b][q][kt], 1 MB

// LDS: sK0@0 sK1@16384 (K dbuf only; V goes global->VGPR direct)
// epilogue: pOx@32768 f32[128][132]=67584 (ends 100352); sO2t aliases @32768
//           sOh@100352 bf16[128][136]=34816 (ends 135168); lws@135168 (1 KB)
#define SMEM_BYTES 136192
#define POX_OFF 32768
#define POX_STRIDE 132
#define SOH_OFF 100352
#define SOH_STRIDE 136
#define SO2_STRIDE 136
#define LWS_OFF 135168

__device__ __forceinline__ void dma16(const void* g, void* l) {
    __builtin_amdgcn_global_load_lds(
        (const __attribute__((address_space(1))) u32*)g,
        (__attribute__((address_space(3))) u32*)l, 16, 0, 0);
}

__device__ __forceinline__ f32x4 mfma32(bf16x8 a, bf16x8 b, f32x4 c) {
    return __builtin_amdgcn_mfma_f32_16x16x32_bf16(a, b, c, 0, 0, 0);
}

__device__ __forceinline__ f32x4 mfma16(bf16x4 a, bf16x4 b, f32x4 c) {
#if __has_builtin(__builtin_amdgcn_mfma_f32_16x16x16_bf16)
    return __builtin_amdgcn_mfma_f32_16x16x16_bf16(a, b, c, 0, 0, 0);
#else
    s16x4 as = __builtin_bit_cast(s16x4, a);
    s16x4 bs = __builtin_bit_cast(s16x4, b);
    return __builtin_amdgcn_mfma_f32_16x16x16bf16_1k(as, bs, c, 0, 0, 0);
#endif
}

__device__ __forceinline__ float fast_exp2(float x) {
#if __has_builtin(__builtin_amdgcn_exp2f)
    return __builtin_amdgcn_exp2f(x);
#else
    return exp2f(x);
#endif
}

// ---- fused prep: mask bitpack (0..8191), K cvt+swz (8192..8447), V frags (8448..8511)
__global__ __launch_bounds__(256)
void prep_all(const float* __restrict__ XK, const float* __restrict__ XV,
              const int* __restrict__ mask, bf16* __restrict__ Kb,
              bf16* __restrict__ Vtb, u64* __restrict__ bits)
{
    const int bid = blockIdx.x;
    const int tid = threadIdx.x;
    if (bid < 8192) {
        int wv = bid * 4 + (tid >> 6);
        int lane = tid & 63;
        size_t base = (size_t)wv * 256;
        #pragma unroll
        for (int s = 0; s < 4; ++s) {
            int m = mask[base + s * 64 + lane];
            u64 bal = __ballot(m != 0);
            if (lane == 0) bits[(size_t)wv * 4 + s] = bal;
        }
    } else if (bid < 8448) {
        // K -> bf16, 16B chunks XOR-swizzled within each 256B row
        int gid = (bid - 8192) * 256 + tid;
        int row = gid >> 4;
        int j   = gid & 15;
        const float* src = XK + (size_t)row * 128 + j * 8;
        float4 v0 = *(const float4*)src;
        float4 v1 = *(const float4*)(src + 4);
        bf16x8 w;
        w[0] = (bf16)v0.x; w[1] = (bf16)v0.y; w[2] = (bf16)v0.z; w[3] = (bf16)v0.w;
        w[4] = (bf16)v1.x; w[5] = (bf16)v1.y; w[6] = (bf16)v1.z; w[7] = (bf16)v1.w;
        int jp = j ^ (row & 15);
        *(bf16x8*)(Kb + (size_t)row * 128 + jp * 8) = w;
    } else {
        // V fragment blocks: [tile][fblk=fi*2+kh][lane] 16B each:
        //   bytes j=0..3 : V[kt*64 + kh*32 +    quad*4 + j][fi*16 + c]
        //   bytes j=4..7 : V[kt*64 + kh*32 + 16 + quad*4 + (j-4)][fi*16 + c]
        int tile = bid - 8448;                 // 0..63 = b*32 + kt
        int bb = tile >> 5, kt = tile & 31;
        #pragma unroll
        for (int i = 0; i < 4; ++i) {
            int idx  = tid * 4 + i;            // 0..1023
            int fblk = idx >> 6;               // fi*2+kh
            int lane = idx & 63;
            int c = lane & 15, quad = lane >> 4;
            int fi = fblk >> 1, kh = fblk & 1;
            int f = fi * 16 + c;
            int kb = kt * 64 + kh * 32 + quad * 4;
            bf16x8 w;
            #pragma unroll
            for (int j = 0; j < 4; ++j) {
                w[j]     = (bf16)XV[(size_t)(bb * L_ + kb + j) * F_ + f];
                w[4 + j] = (bf16)XV[(size_t)(bb * L_ + kb + 16 + j) * F_ + f];
            }
            *(bf16x8*)(Vtb + (size_t)tile * 8192 + fblk * 512 + lane * 8) = w;
        }
    }
}

// ---- main fused kernel: 512 thr / 8 waves; wave = (kh, msel) owns 32k x 32m ----
__global__ __launch_bounds__(512, 2)
void attn_fused_kernel(const float* __restrict__ XQ, const bf16* __restrict__ Kb,
                       const bf16* __restrict__ Vtb, const u64* __restrict__ bits,
                       const float* __restrict__ WQ, const float* __restrict__ WK,
                       const float* __restrict__ WV, const float* __restrict__ Om,
                       float* __restrict__ out)
{
    __shared__ __align__(16) char smem[SMEM_BYTES];
    __shared__ __align__(16) float g_s[128];

    bf16* sK0  = (bf16*)smem;
    bf16* sK1  = (bf16*)(smem + 16384);
    float* pOx = (float*)(smem + POX_OFF);
    bf16* sO2t = (bf16*)(smem + POX_OFF);     // aliases pOx (after consumed)
    bf16* sOh  = (bf16*)(smem + SOH_OFF);
    float* lws = (float*)(smem + LWS_OFF);

    const int tid  = threadIdx.x;
    const int wave = tid >> 6;        // 0..7
    const int lane = tid & 63;
    const int c    = lane & 15;
    const int quad = lane >> 4;
    const int qt = blockIdx.x, h = blockIdx.y, b = blockIdx.z;
    const int q0 = qt * QT;

    const int kh   = wave >> 2;       // k-half of each 64k tile
    const int msel = wave & 3;        // m-pair (32 q rows)
    const int fv  = tid & 127;
    const int grp = tid >> 7;         // 0..3

    // g = diag(WQ)*diag(WK)/sqrt(D) * log2(e)  (exp computed as exp2)
    if (tid < 128) {
        float wq = WQ[(h * D_ + tid) * D_ + tid];
        float wk = WK[(h * D_ + tid) * D_ + tid];
        g_s[tid] = wq * wk * 0.12752230502179406f;
    }
    __syncthreads();

    const char* gK = (const char*)Kb + (size_t)(b * L_) * 256;       // 16 KB/tile
    const char* gV = (const char*)Vtb + (size_t)(b * NKT) * 16384;   // 16 KB/tile

    // DMA K tile 0
    dma16(gK + tid * 16, (char*)sK0 + tid * 16);
    dma16(gK + 8192 + tid * 16, (char*)sK0 + 8192 + tid * 16);

    // Q fragments (2 m-tiles), scaled, loop-invariant
    bf16x8 qfrag[2][4];
    #pragma unroll
    for (int mi = 0; mi < 2; ++mi) {
        const float* qrow = XQ + (size_t)(b * L_ + q0 + msel * 32 + mi * 16 + c) * D_;
        #pragma unroll
        for (int kc = 0; kc < 4; ++kc) {
            int d0 = kc * 32 + quad * 8;
            float4 v0 = *(const float4*)(qrow + d0);
            float4 v1 = *(const float4*)(qrow + d0 + 4);
            float4 g0 = *(const float4*)(g_s + d0);
            float4 g1 = *(const float4*)(g_s + d0 + 4);
            bf16x8 w;
            w[0] = (bf16)(v0.x * g0.x); w[1] = (bf16)(v0.y * g0.y);
            w[2] = (bf16)(v0.z * g0.z); w[3] = (bf16)(v0.w * g0.w);
            w[4] = (bf16)(v1.x * g1.x); w[5] = (bf16)(v1.y * g1.y);
            w[6] = (bf16)(v1.z * g1.z); w[7] = (bf16)(v1.w * g1.w);
            qfrag[mi][kc] = w;
        }
    }

    f32x4 oacc[2][8];
    #pragma unroll
    for (int mi = 0; mi < 2; ++mi)
        #pragma unroll
        for (int fi = 0; fi < 8; ++fi)
            #pragma unroll
            for (int r = 0; r < 4; ++r) oacc[mi][fi][r] = 0.f;
    float lsum[2] = {0.f, 0.f};

    const u64* mrow0 = bits + (size_t)(b * L_ + q0 + msel * 32 + c) * NKT;
    const u64* mrow1 = mrow0 + (size_t)16 * NKT;

    #pragma unroll 2
    for (int kt = 0; kt < NKT; ++kt) {
        bf16* sK  = (kt & 1) ? sK1 : sK0;
        bf16* sKn = (kt & 1) ? sK0 : sK1;

        // A: all waves done reading sK[next]
        asm volatile("s_barrier" ::: "memory");

        // V fragments for this tile: 8 global b128 (L1/L2), consumed in PV
        bf16x8 vload[8];
        {
            const char* gvt = gV + (size_t)kt * 16384 + kh * 1024 + lane * 16;
            #pragma unroll
            for (int fi = 0; fi < 8; ++fi)
                vload[fi] = *(const bf16x8*)(gvt + fi * 2048);
        }
        u64 mb0 = mrow0[kt];
        u64 mb1 = mrow1[kt];

        if (kt + 1 < NKT) {
            const char* gkn = gK + (size_t)(kt + 1) * 16384;
            dma16(gkn + tid * 16, (char*)sKn + tid * 16);
            dma16(gkn + 8192 + tid * 16, (char*)sKn + 8192 + tid * 16);
            // newer = 8 vload + 2 mask + 2 next-DMA = 12 -> tile kt's K-DMA drained
            asm volatile("s_waitcnt vmcnt(12)" ::: "memory");
        } else {
            asm volatile("s_waitcnt vmcnt(10)" ::: "memory");
        }
        // B: K tile kt resident
        asm volatile("s_barrier" ::: "memory");

        // S^T = K @ Qg^T : 2 k-tiles x 2 m-tiles, kfrag reused x2
        f32x4 tacc[2][2];
        #pragma unroll
        for (int mi = 0; mi < 2; ++mi)
            #pragma unroll
            for (int kti = 0; kti < 2; ++kti)
                #pragma unroll
                for (int r = 0; r < 4; ++r) tacc[mi][kti][r] = 0.f;

        #pragma unroll
        for (int kti = 0; kti < 2; ++kti) {
            const bf16* krow = sK + ((kh * 2 + kti) * 16 + c) * 128;
            #pragma unroll
            for (int kc = 0; kc < 4; ++kc) {
                bf16x8 kfrag = *(const bf16x8*)(krow + (((kc * 4 + quad) ^ c) * 8));
                tacc[0][kti] = mfma32(kfrag, qfrag[0][kc], tacc[0][kti]);
                tacc[1][kti] = mfma32(kfrag, qfrag[1][kc], tacc[1][kti]);
            }
        }

        // exp2 (scale folded into g) -> P directly in A-operand layout of mfma16
        bf16x4 pfrag[2][2];
        #pragma unroll
        for (int mi = 0; mi < 2; ++mi) {
            u64 mb = mi ? mb1 : mb0;
            #pragma unroll
            for (int kti = 0; kti < 2; ++kti) {
                #pragma unroll
                for (int r = 0; r < 4; ++r) {
                    int pos = kh * 32 + kti * 16 + quad * 4 + r;
                    float p = ((mb >> pos) & 1ull) ? fast_exp2(tacc[mi][kti][r]) : 0.f;
                    lsum[mi] += p;
                    pfrag[mi][kti][r] = (bf16)p;
                }
            }
        }

        // O += P @ V : vfrag (registers, from global) reused x2 m-tiles
        #pragma unroll
        for (int fi = 0; fi < 8; ++fi) {
            bf16x4 v0 = __builtin_shufflevector(vload[fi], vload[fi], 0, 1, 2, 3);
            bf16x4 v1 = __builtin_shufflevector(vload[fi], vload[fi], 4, 5, 6, 7);
            #pragma unroll
            for (int mi = 0; mi < 2; ++mi) {
                oacc[mi][fi] = mfma16(pfrag[mi][0], v0, oacc[mi][fi]);
                oacc[mi][fi] = mfma16(pfrag[mi][1], v1, oacc[mi][fi]);
            }
        }
    }

    // per-wave row sums over its 32k: reduce across quads, publish
    #pragma unroll
    for (int mi = 0; mi < 2; ++mi) {
        float v = lsum[mi];
        v += __shfl_xor(v, 16); v += __shfl_xor(v, 32);
        if (lane < 16) lws[wave * 32 + mi * 16 + lane] = v;
    }
    if (tid < 128)
        g_s[tid] = WV[(h * F_ + tid) * F_ + tid];   // dv
    __syncthreads();   // loop LDS reads done; lws + g_s visible

    // kh=1 waves: dump partial O (f32)
    if (kh == 1) {
        #pragma unroll
        for (int mi = 0; mi < 2; ++mi)
            #pragma unroll
            for (int fi = 0; fi < 8; ++fi)
                #pragma unroll
                for (int r = 0; r < 4; ++r)
                    pOx[(msel * 32 + mi * 16 + quad * 4 + r) * POX_STRIDE + fi * 16 + c]
                        = oacc[mi][fi][r];
    }
    __syncthreads();

    // kh=0 waves: combine halves, normalize, write Oh (bf16)
    if (kh == 0) {
        #pragma unroll
        for (int mi = 0; mi < 2; ++mi) {
            float linv[4];
            #pragma unroll
            for (int r = 0; r < 4; ++r) {
                int s = mi * 16 + quad * 4 + r;
                linv[r] = 1.0f / (lws[msel * 32 + s] + lws[(4 + msel) * 32 + s]);
            }
            #pragma unroll
            for (int fi = 0; fi < 8; ++fi)
                #pragma unroll
                for (int r = 0; r < 4; ++r) {
                    int row = msel * 32 + mi * 16 + quad * 4 + r;
                    float v = (oacc[mi][fi][r] + pOx[row * POX_STRIDE + fi * 16 + c]) * linv[r];
                    sOh[row * SOH_STRIDE + fi * 16 + c] = (bf16)v;
                }
        }
    }
    __syncthreads();   // pOx consumed -> sO2t region free

    // stage O2^T: sO2t[f][f'] = O[h*128+f'][f] * dv[f']
    #pragma unroll
    for (int i = 0; i < 8; ++i) {
        int fp4 = grp * 32 + i * 4;
        bf16x4 w;
        #pragma unroll
        for (int j = 0; j < 4; ++j) {
            int x = fp4 + j;
            w[j] = (bf16)(Om[(h * F_ + x) * F_ + fv] * g_s[x]);
        }
        *(bf16x4*)(sO2t + fv * SO2_STRIDE + fp4) = w;
    }
    __syncthreads();

    // out_partial = Oh @ O2 (128x128x128): wave pm = m-tile
    const int pm = wave;
    bf16x8 afr[4];
    const bf16* ohrow = sOh + (pm * 16 + c) * SOH_STRIDE;
    #pragma unroll
    for (int kc = 0; kc < 4; ++kc)
        afr[kc] = *(const bf16x8*)(ohrow + kc * 32 + quad * 8);

    #pragma unroll
    for (int nt = 0; nt < 8; ++nt) {
        f32x4 pacc;
        #pragma unroll
        for (int r = 0; r < 4; ++r) pacc[r] = 0.f;
        const bf16* orow = sO2t + (nt * 16 + c) * SO2_STRIDE;
        #pragma unroll
        for (int kc = 0; kc < 4; ++kc) {
            bf16x8 bfrag = *(const bf16x8*)(orow + kc * 32 + quad * 8);
            pacc = mfma32(afr[kc], bfrag, pacc);
        }
        #pragma unroll
        for (int r = 0; r < 4; ++r) {
            int qg = q0 + pm * 16 + quad * 4 + r;
            atomicAdd(out + ((size_t)(b * L_ + qg) * F_ + nt * 16 + c), pacc[r]);
        }
    }
}

extern "C" void kernel_launch(void* const* d_in, const int* in_sizes, int n_in,
                              void* d_out, int out_size, void* d_ws, size_t ws_size,
                              hipStream_t stream) {
    const float* XQ   = (const float*)d_in[0];
    const float* XK   = (const float*)d_in[1];
    const float* XV   = (const float*)d_in[2];
    const int*   mask = (const int*)d_in[3];
    const float* WQ   = (const float*)d_in[4];
    const float* WK   = (const float*)d_in[5];
    const float* WV   = (const float*)d_in[6];
    const float* Om   = (const float*)d_in[7];
    float* out = (float*)d_out;

    char* ws = (char*)d_ws;
    bf16* Kb   = (bf16*)(ws + WS_KB);
    bf16* Vtb  = (bf16*)(ws + WS_VT);
    u64*  bits = (u64*)(ws + WS_MB);

    prep_all<<<8512, 256, 0, stream>>>(XK, XV, mask, Kb, Vtb, bits);
    hipMemsetAsync(out, 0, (size_t)out_size * sizeof(float), stream);

    dim3 grid(NQT, H_, B_);
    attn_fused_kernel<<<grid, 512, 0, stream>>>(XQ, Kb, Vtb, bits, WQ, WK, WV, Om, out);
}

// Round 8
// 176.028 us; speedup vs baseline: 1.0269x; 1.0269x over previous
//
#include <hip/hip_runtime.h>

typedef __bf16 bf16;
typedef __bf16 bf16x4 __attribute__((ext_vector_type(4)));
typedef __bf16 bf16x8 __attribute__((ext_vector_type(8)));
typedef float f32x4 __attribute__((ext_vector_type(4)));
typedef short s16x4 __attribute__((ext_vector_type(4)));
typedef unsigned int u32;
typedef unsigned long long u64;

#define B_ 2
#define H_ 8
#define L_ 2048
#define D_ 128
#define F_ 128
#define QT 128
#define KT 64
#define NKT (L_ / KT)
#define NQT (L_ / QT)

// workspace layout (bytes)
#define WS_KB 0u            // Kb  : bf16 [b][k][16B-chunk swizzled], 1 MB
#define WS_VT (1u << 20)    // Vtb : bf16 [b][kt][f][pair swizzled], 1 MB
#define WS_MB (2u << 20)    // bits: u64 [b][q][kt], 1 MB

// LDS main: sK0@0 sK1@16384 sV0@32768 sV1@49152 (16 KB each)
// epilogue: pOx@0 f32[64][132]=33792 (2 phases) ; sOh@36864 bf16[128][136]=34816
//           (ends 71680) ; lws@71680 (1 KB) ; sO2t aliases pOx @0 after consumed
#define SMEM_BYTES 72704
#define POX_STRIDE 132
#define SOH_OFF 36864
#define SOH_STRIDE 136
#define SO2_STRIDE 136
#define LWS_OFF 71680

__device__ __forceinline__ void dma16(const void* g, void* l) {
    __builtin_amdgcn_global_load_lds(
        (const __attribute__((address_space(1))) u32*)g,
        (__attribute__((address_space(3))) u32*)l, 16, 0, 0);
}

__device__ __forceinline__ f32x4 mfma32(bf16x8 a, bf16x8 b, f32x4 c) {
    return __builtin_amdgcn_mfma_f32_16x16x32_bf16(a, b, c, 0, 0, 0);
}

__device__ __forceinline__ f32x4 mfma16(bf16x4 a, bf16x4 b, f32x4 c) {
#if __has_builtin(__builtin_amdgcn_mfma_f32_16x16x16_bf16)
    return __builtin_amdgcn_mfma_f32_16x16x16_bf16(a, b, c, 0, 0, 0);
#else
    s16x4 as = __builtin_bit_cast(s16x4, a);
    s16x4 bs = __builtin_bit_cast(s16x4, b);
    return __builtin_amdgcn_mfma_f32_16x16x16bf16_1k(as, bs, c, 0, 0, 0);
#endif
}

__device__ __forceinline__ float fast_exp2(float x) {
#if __has_builtin(__builtin_amdgcn_exp2f)
    return __builtin_amdgcn_exp2f(x);
#else
    return exp2f(x);
#endif
}

// ---- fused prep: mask bitpack (0..8191), K cvt+swz (8192..8447), V pairs (8448..8511)
__global__ __launch_bounds__(256)
void prep_all(const float* __restrict__ XK, const float* __restrict__ XV,
              const int* __restrict__ mask, bf16* __restrict__ Kb,
              bf16* __restrict__ Vtb, u64* __restrict__ bits)
{
    const int bid = blockIdx.x;
    const int tid = threadIdx.x;
    if (bid < 8192) {
        int wv = bid * 4 + (tid >> 6);
        int lane = tid & 63;
        size_t base = (size_t)wv * 256;
        #pragma unroll
        for (int s = 0; s < 4; ++s) {
            int m = mask[base + s * 64 + lane];
            u64 bal = __ballot(m != 0);
            if (lane == 0) bits[(size_t)wv * 4 + s] = bal;
        }
    } else if (bid < 8448) {
        // K -> bf16, 16B chunks XOR-swizzled within each 256B row
        int gid = (bid - 8192) * 256 + tid;
        int row = gid >> 4;
        int j   = gid & 15;
        const float* src = XK + (size_t)row * 128 + j * 8;
        float4 v0 = *(const float4*)src;
        float4 v1 = *(const float4*)(src + 4);
        bf16x8 w;
        w[0] = (bf16)v0.x; w[1] = (bf16)v0.y; w[2] = (bf16)v0.z; w[3] = (bf16)v0.w;
        w[4] = (bf16)v1.x; w[5] = (bf16)v1.y; w[6] = (bf16)v1.z; w[7] = (bf16)v1.w;
        int jp = j ^ (row & 15);
        *(bf16x8*)(Kb + (size_t)row * 128 + jp * 8) = w;
    } else {
        // V^T pair tiles: [tile][f][pair p = kh*4+quad] 16B:
        //   bytes 0-7 : V[kt*64 + kh*32 +      quad*4 + j][f]   (kti=0)
        //   bytes 8-15: V[kt*64 + kh*32 + 16 + quad*4 + j][f]   (kti=1)
        // pair stored at p ^ (f & 7)
        int tile = bid - 8448;                 // 0..63 = b*32 + kt
        int bb = tile >> 5, kt = tile & 31;
        #pragma unroll
        for (int i = 0; i < 4; ++i) {
            int idx = tid * 4 + i;             // 0..1023 = f*8 + p
            int f = idx >> 3, p = idx & 7;
            int kh = p >> 2, quad = p & 3;
            int kb = kt * 64 + kh * 32 + quad * 4;
            const float* src = XV + (size_t)(bb * L_ + kb) * F_ + f;
            bf16x8 w;
            #pragma unroll
            for (int j = 0; j < 4; ++j) {
                w[j]     = (bf16)src[(size_t)j * F_];
                w[4 + j] = (bf16)src[(size_t)(16 + j) * F_];
            }
            *(bf16x8*)(Vtb + (size_t)tile * 8192 + f * 64 + ((p ^ (f & 7)) * 8)) = w;
        }
    }
}

// ---- main fused kernel: 512 thr / 8 waves; wave = (kh, msel) owns 32k x 32m ----
__global__ __launch_bounds__(512, 2)
void attn_fused_kernel(const float* __restrict__ XQ, const bf16* __restrict__ Kb,
                       const bf16* __restrict__ Vtb, const u64* __restrict__ bits,
                       const float* __restrict__ WQ, const float* __restrict__ WK,
                       const float* __restrict__ WV, const float* __restrict__ Om,
                       float* __restrict__ out)
{
    __shared__ __align__(16) char smem[SMEM_BYTES];
    __shared__ __align__(16) float g_s[128];

    bf16* sK0  = (bf16*)smem;
    bf16* sK1  = (bf16*)(smem + 16384);
    bf16* sV0  = (bf16*)(smem + 32768);
    bf16* sV1  = (bf16*)(smem + 49152);
    float* pOx = (float*)smem;                 // epilogue (2 phases)
    bf16* sO2t = (bf16*)smem;                  // epilogue, after pOx consumed
    bf16* sOh  = (bf16*)(smem + SOH_OFF);
    float* lws = (float*)(smem + LWS_OFF);

    const int tid  = threadIdx.x;
    const int wave = tid >> 6;        // 0..7
    const int lane = tid & 63;
    const int c    = lane & 15;
    const int quad = lane >> 4;
    const int qt = blockIdx.x, h = blockIdx.y, b = blockIdx.z;
    const int q0 = qt * QT;

    const int kh   = wave >> 2;       // k-half of the 64k tile
    const int msel = wave & 3;        // m-pair (32 q rows)
    const int fv  = tid & 127;
    const int grp = tid >> 7;         // 0..3

    // g = diag(WQ)*diag(WK)/sqrt(D) * log2(e)
    if (tid < 128) {
        float wq = WQ[(h * D_ + tid) * D_ + tid];
        float wk = WK[(h * D_ + tid) * D_ + tid];
        g_s[tid] = wq * wk * 0.12752230502179406f;
    }
    __syncthreads();

    const char* gK = (const char*)Kb + (size_t)(b * L_) * 256;       // 16 KB/tile
    const char* gV = (const char*)Vtb + (size_t)(b * NKT) * 16384;   // 16 KB/tile

    // DMA tile 0 (K + V)
    dma16(gK + tid * 16, (char*)sK0 + tid * 16);
    dma16(gK + 8192 + tid * 16, (char*)sK0 + 8192 + tid * 16);
    dma16(gV + tid * 16, (char*)sV0 + tid * 16);
    dma16(gV + 8192 + tid * 16, (char*)sV0 + 8192 + tid * 16);

    // Q fragments (2 m-tiles), scaled, loop-invariant
    bf16x8 qfrag[2][4];
    #pragma unroll
    for (int mi = 0; mi < 2; ++mi) {
        const float* qrow = XQ + (size_t)(b * L_ + q0 + msel * 32 + mi * 16 + c) * D_;
        #pragma unroll
        for (int kc = 0; kc < 4; ++kc) {
            int d0 = kc * 32 + quad * 8;
            float4 v0 = *(const float4*)(qrow + d0);
            float4 v1 = *(const float4*)(qrow + d0 + 4);
            float4 g0 = *(const float4*)(g_s + d0);
            float4 g1 = *(const float4*)(g_s + d0 + 4);
            bf16x8 w;
            w[0] = (bf16)(v0.x * g0.x); w[1] = (bf16)(v0.y * g0.y);
            w[2] = (bf16)(v0.z * g0.z); w[3] = (bf16)(v0.w * g0.w);
            w[4] = (bf16)(v1.x * g1.x); w[5] = (bf16)(v1.y * g1.y);
            w[6] = (bf16)(v1.z * g1.z); w[7] = (bf16)(v1.w * g1.w);
            qfrag[mi][kc] = w;
        }
    }

    f32x4 oacc[2][8];
    #pragma unroll
    for (int mi = 0; mi < 2; ++mi)
        #pragma unroll
        for (int fi = 0; fi < 8; ++fi)
            #pragma unroll
            for (int r = 0; r < 4; ++r) oacc[mi][fi][r] = 0.f;
    float lsum[2] = {0.f, 0.f};

    const u64* mrow0 = bits + (size_t)(b * L_ + q0 + msel * 32 + c) * NKT;
    const u64* mrow1 = mrow0 + (size_t)16 * NKT;

    const int psw = ((kh * 4 + quad) ^ (c & 7)) * 8;   // V pair offset (elems)

    #pragma unroll 2
    for (int kt = 0; kt < NKT; ++kt) {
        bf16* sK  = (kt & 1) ? sK1 : sK0;
        bf16* sV  = (kt & 1) ? sV1 : sV0;
        bf16* sKn = (kt & 1) ? sK0 : sK1;
        bf16* sVn = (kt & 1) ? sV0 : sV1;

        // A: all waves done reading buf[next]
        asm volatile("s_barrier" ::: "memory");

        u64 mb0 = mrow0[kt];
        u64 mb1 = mrow1[kt];

        if (kt + 1 < NKT) {
            const char* gkn = gK + (size_t)(kt + 1) * 16384;
            const char* gvn = gV + (size_t)(kt + 1) * 16384;
            dma16(gkn + tid * 16, (char*)sKn + tid * 16);
            dma16(gkn + 8192 + tid * 16, (char*)sKn + 8192 + tid * 16);
            dma16(gvn + tid * 16, (char*)sVn + tid * 16);
            dma16(gvn + 8192 + tid * 16, (char*)sVn + 8192 + tid * 16);
            // newest 6 = 2 mask + 4 next-DMA -> tile kt's 4 DMA drained
            asm volatile("s_waitcnt vmcnt(6)" ::: "memory");
        } else {
            asm volatile("s_waitcnt vmcnt(2)" ::: "memory");
        }
        // B: tile kt resident
        asm volatile("s_barrier" ::: "memory");

        // S^T = K @ Qg^T : 2 k-tiles x 2 m-tiles, kfrag reused x2
        f32x4 tacc[2][2];
        #pragma unroll
        for (int mi = 0; mi < 2; ++mi)
            #pragma unroll
            for (int kti = 0; kti < 2; ++kti)
                #pragma unroll
                for (int r = 0; r < 4; ++r) tacc[mi][kti][r] = 0.f;

        #pragma unroll
        for (int kti = 0; kti < 2; ++kti) {
            const bf16* krow = sK + ((kh * 2 + kti) * 16 + c) * 128;
            #pragma unroll
            for (int kc = 0; kc < 4; ++kc) {
                bf16x8 kfrag = *(const bf16x8*)(krow + (((kc * 4 + quad) ^ c) * 8));
                tacc[0][kti] = mfma32(kfrag, qfrag[0][kc], tacc[0][kti]);
                tacc[1][kti] = mfma32(kfrag, qfrag[1][kc], tacc[1][kti]);
            }
        }

        // exp2 (scale folded into g) -> P directly in A-operand layout of mfma16
        bf16x4 pfrag[2][2];
        #pragma unroll
        for (int mi = 0; mi < 2; ++mi) {
            u64 mb = mi ? mb1 : mb0;
            #pragma unroll
            for (int kti = 0; kti < 2; ++kti) {
                #pragma unroll
                for (int r = 0; r < 4; ++r) {
                    int pos = kh * 32 + kti * 16 + quad * 4 + r;
                    float p = ((mb >> pos) & 1ull) ? fast_exp2(tacc[mi][kti][r]) : 0.f;
                    lsum[mi] += p;
                    pfrag[mi][kti][r] = (bf16)p;
                }
            }
        }

        // O += P @ V : paired vfrag (one b128 = both kti), reused x2 m-tiles
        #pragma unroll
        for (int fi = 0; fi < 8; ++fi) {
            bf16x8 vp = *(const bf16x8*)(sV + (fi * 16 + c) * 64 + psw);
            bf16x4 v0 = __builtin_shufflevector(vp, vp, 0, 1, 2, 3);
            bf16x4 v1 = __builtin_shufflevector(vp, vp, 4, 5, 6, 7);
            #pragma unroll
            for (int mi = 0; mi < 2; ++mi) {
                oacc[mi][fi] = mfma16(pfrag[mi][0], v0, oacc[mi][fi]);
                oacc[mi][fi] = mfma16(pfrag[mi][1], v1, oacc[mi][fi]);
            }
        }
    }

    // per-wave row sums over its 32k: reduce across quads, publish
    #pragma unroll
    for (int mi = 0; mi < 2; ++mi) {
        float v = lsum[mi];
        v += __shfl_xor(v, 16); v += __shfl_xor(v, 32);
        if (lane < 16) lws[wave * 32 + mi * 16 + lane] = v;
    }
    if (tid < 128)
        g_s[tid] = WV[(h * F_ + tid) * F_ + tid];   // dv
    __syncthreads();   // main-loop LDS reads done; lws + g_s visible

    // two phases (mi = 0,1): kh=1 dumps partial O (f32), kh=0 combines+normalizes
    #pragma unroll
    for (int mi = 0; mi < 2; ++mi) {
        if (kh == 1) {
            #pragma unroll
            for (int fi = 0; fi < 8; ++fi)
                #pragma unroll
                for (int r = 0; r < 4; ++r)
                    pOx[(msel * 16 + quad * 4 + r) * POX_STRIDE + fi * 16 + c]
                        = oacc[mi][fi][r];
        }
        __syncthreads();
        if (kh == 0) {
            float linv[4];
            #pragma unroll
            for (int r = 0; r < 4; ++r) {
                int s = mi * 16 + quad * 4 + r;
                linv[r] = 1.0f / (lws[msel * 32 + s] + lws[(4 + msel) * 32 + s]);
            }
            #pragma unroll
            for (int fi = 0; fi < 8; ++fi)
                #pragma unroll
                for (int r = 0; r < 4; ++r) {
                    int row_c = msel * 16 + quad * 4 + r;
                    int row_q = msel * 32 + mi * 16 + quad * 4 + r;
                    float v = (oacc[mi][fi][r] + pOx[row_c * POX_STRIDE + fi * 16 + c]) * linv[r];
                    sOh[row_q * SOH_STRIDE + fi * 16 + c] = (bf16)v;
                }
        }
        __syncthreads();
    }

    // stage O2^T: sO2t[f][f'] = O[h*128+f'][f] * dv[f']  (pOx region free)
    #pragma unroll
    for (int i = 0; i < 8; ++i) {
        int fp4 = grp * 32 + i * 4;
        bf16x4 w;
        #pragma unroll
        for (int j = 0; j < 4; ++j) {
            int x = fp4 + j;
            w[j] = (bf16)(Om[(h * F_ + x) * F_ + fv] * g_s[x]);
        }
        *(bf16x4*)(sO2t + fv * SO2_STRIDE + fp4) = w;
    }
    __syncthreads();

    // out_partial = Oh @ O2 (128x128x128): wave pm = m-tile
    const int pm = wave;
    bf16x8 afr[4];
    const bf16* ohrow = sOh + (pm * 16 + c) * SOH_STRIDE;
    #pragma unroll
    for (int kc = 0; kc < 4; ++kc)
        afr[kc] = *(const bf16x8*)(ohrow + kc * 32 + quad * 8);

    #pragma unroll
    for (int nt = 0; nt < 8; ++nt) {
        f32x4 pacc;
        #pragma unroll
        for (int r = 0; r < 4; ++r) pacc[r] = 0.f;
        const bf16* orow = sO2t + (nt * 16 + c) * SO2_STRIDE;
        #pragma unroll
        for (int kc = 0; kc < 4; ++kc) {
            bf16x8 bfrag = *(const bf16x8*)(orow + kc * 32 + quad * 8);
            pacc = mfma32(afr[kc], bfrag, pacc);
        }
        #pragma unroll
        for (int r = 0; r < 4; ++r) {
            int qg = q0 + pm * 16 + quad * 4 + r;
            atomicAdd(out + ((size_t)(b * L_ + qg) * F_ + nt * 16 + c), pacc[r]);
        }
    }
}

extern "C" void kernel_launch(void* const* d_in, const int* in_sizes, int n_in,
                              void* d_out, int out_size, void* d_ws, size_t ws_size,
                              hipStream_t stream) {
    const float* XQ   = (const float*)d_in[0];
    const float* XK   = (const float*)d_in[1];
    const float* XV   = (const float*)d_in[2];
    const int*   mask = (const int*)d_in[3];
    const float* WQ   = (const float*)d_in[4];
    const float* WK   = (const float*)d_in[5];
    const float* WV   = (const float*)d_in[6];
    const float* Om   = (const float*)d_in[7];
    float* out = (float*)d_out;

    char* ws = (char*)d_ws;
    bf16* Kb   = (bf16*)(ws + WS_KB);
    bf16* Vtb  = (bf16*)(ws + WS_VT);
    u64*  bits = (u64*)(ws + WS_MB);

    prep_all<<<8512, 256, 0, stream>>>(XK, XV, mask, Kb, Vtb, bits);
    hipMemsetAsync(out, 0, (size_t)out_size * sizeof(float), stream);

    dim3 grid(NQT, H_, B_);
    attn_fused_kernel<<<grid, 512, 0, stream>>>(XQ, Kb, Vtb, bits, WQ, WK, WV, Om, out);
}